// Round 16
// baseline (120.882 us; speedup 1.0000x reference)
//
#include <hip/hip_runtime.h>
#include <hip/hip_cooperative_groups.h>

namespace cg = cooperative_groups;

typedef float f4 __attribute__((ext_vector_type(4)));
typedef float f2 __attribute__((ext_vector_type(2)));
typedef short short8 __attribute__((ext_vector_type(8)));
typedef float f32x4 __attribute__((ext_vector_type(4)));

#define NEG_INF -1e9f

__device__ inline void bsplit(float x, unsigned short& h, unsigned short& l) {
  union { float f; unsigned u; } a; a.f = x;
  unsigned rh = (a.u + 0x7fffu + ((a.u >> 16) & 1u)) >> 16;
  h = (unsigned short)rh;
  union { unsigned u; float f; } b; b.u = rh << 16;
  union { float f; unsigned u; } c; c.f = x - b.f;
  unsigned rl = (c.u + 0x7fffu + ((c.u >> 16) & 1u)) >> 16;
  l = (unsigned short)rl;
}

__device__ inline void gl_lds16(const void* g, void* l) {
  __builtin_amdgcn_global_load_lds(
      (const __attribute__((address_space(1))) unsigned int*)g,
      (__attribute__((address_space(3))) unsigned int*)l, 16, 0, 0);
}

// ---------------------------------------------------------------------------
// bah_fused: conv (P1) -> grid.sync -> projmm split-K (P2) -> grid.sync ->
// attn (P3, R15-exact body). 256 blocks x 1024 thr, 1 block/CU co-resident.
// ---------------------------------------------------------------------------
__global__ __launch_bounds__(1024) void bah_fused(
    const float* __restrict__ query, const float* __restrict__ value,
    const int* __restrict__ mask,
    const float* __restrict__ W1, const float* __restrict__ W2,
    const float* __restrict__ scale,
    unsigned short* __restrict__ Ahi, unsigned short* __restrict__ Alo,
    unsigned short* __restrict__ Whi, unsigned short* __restrict__ Wlo,
    float* __restrict__ EQ, float* __restrict__ EKT,
    float* __restrict__ ctx_out, float* __restrict__ attn_out)
{
  const int blk = blockIdx.x;
  const int tid = threadIdx.x;

  __shared__ f4    eq4s[512];            //  8 KB
  __shared__ float ss[512];              //  2 KB
  __shared__ float wredM[4][4];
  __shared__ float wredS[4][4];
  __shared__ float sumS_lds;
  __shared__ float atT[256][4];          //  4 KB
  __shared__ __align__(16) char uA[131072];   // phase-aliased 128 KB

  // ======================== Phase 1: conversions ===========================
  if (blk < 128) {
    // conv_a: pack {query rows, value rows} -> A_perm bf16 hi/lo
    const int g = blk * 1024 + tid;                 // 0..131071
    const int row64 = g & 63;
    const int panel = (g >> 6) & 31;
    const int kc    = g >> 11;                      // 0..63
    const int rowg  = panel * 64 + row64;
    const float* src = (rowg < 1024) ? (query + (size_t)rowg * 512 + kc * 8)
                                     : (value + (size_t)(rowg - 1024) * 512 + kc * 8);
    f4 x0 = *reinterpret_cast<const f4*>(src);
    f4 x1 = *reinterpret_cast<const f4*>(src + 4);
    unsigned short h[8], lo[8];
#pragma unroll
    for (int j = 0; j < 4; ++j) { bsplit(x0[j], h[j], lo[j]); bsplit(x1[j], h[4+j], lo[4+j]); }
    const size_t off = ((size_t)(panel * 64 + kc) * 64 + row64) * 8;
    short8 ph, pl;
#pragma unroll
    for (int j = 0; j < 8; ++j) { ph[j] = (short)h[j]; pl[j] = (short)lo[j]; }
    *reinterpret_cast<short8*>(&Ahi[off]) = ph;
    *reinterpret_cast<short8*>(&Alo[off]) = pl;
  } else if (blk < 144) {
    // conv_w: 16 blocks = (np 8, z 2); sub-group sg = kslab (4 x 256 thr)
    const int bid = blk - 128;
    const int np  = bid & 7;
    const int z   = bid >> 3;
    const int sg  = tid >> 8;        // kslab
    const int t   = tid & 255;
    const float* __restrict__ W = z ? W2 : W1;
    const int k0 = sg * 128, n0 = np * 64;
    float* const ldsW = (float*)(uA + sg * 32768);   // [128][64]

#pragma unroll
    for (int it = 0; it < 8; ++it) {
      const int idx = it * 256 + t;
      const int kr  = idx >> 4;
      const int nc4 = (idx & 15) * 4;
      *reinterpret_cast<f4*>(ldsW + kr * 64 + nc4) =
          *reinterpret_cast<const f4*>(&W[(size_t)(k0 + kr) * 512 + n0 + nc4]);
    }
    __syncthreads();

    const int wpanel = z * 8 + np;
    const int n = t & 63;
#pragma unroll
    for (int it = 0; it < 4; ++it) {
      const int kcl = it * 4 + (t >> 6);
      short8 ph, pl;
#pragma unroll
      for (int j = 0; j < 8; ++j) {
        unsigned short h, lo;
        bsplit(ldsW[(kcl * 8 + j) * 64 + n], h, lo);
        ph[j] = (short)h; pl[j] = (short)lo;
      }
      const size_t off = ((size_t)(wpanel * 64 + sg * 16 + kcl) * 64 + n) * 8;
      *reinterpret_cast<short8*>(&Whi[off]) = ph;
      *reinterpret_cast<short8*>(&Wlo[off]) = pl;
    }
  }

  cg::this_grid().sync();

  // ================= Phase 2: projmm, split-K over 4 sub-groups ============
  {
    const int nb = blk & 7, mb = (blk >> 3) & 15, z = blk >> 7;
    const int sg = tid >> 8;         // K-quarter (4 ks steps)
    const int t  = tid & 255;
    const int l  = t & 63;
    const int w4 = t >> 6;
    const int wr = w4 >> 1, wc = w4 & 1;

    const unsigned short* abase_h = Ahi + (size_t)(z * 16 + mb) * 32768;
    const unsigned short* abase_l = Alo + (size_t)(z * 16 + mb) * 32768;
    const unsigned short* wbase_h = Whi + (size_t)(z * 8 + nb) * 32768;
    const unsigned short* wbase_l = Wlo + (size_t)(z * 8 + nb) * 32768;

    char* const sgbase = uA + sg * 32768;   // A: 16 KB, B: 16 KB per sg
    const int gsrc = t * 8;                 // shorts
    const int ldso = (t >> 6) * 1024;       // bytes (wave-uniform)

#define CHA(buf, hl) (sgbase + ((buf) * 2 + (hl)) * 4096)
#define CHB(buf, hl) (sgbase + 16384 + ((buf) * 2 + (hl)) * 4096)
#define PSTAGE(buf, ksg)                                                      \
    do {                                                                      \
      gl_lds16(abase_h + (ksg) * 2048 + gsrc, CHA(buf, 0) + ldso);            \
      gl_lds16(abase_l + (ksg) * 2048 + gsrc, CHA(buf, 1) + ldso);            \
      gl_lds16(wbase_h + (ksg) * 2048 + gsrc, CHB(buf, 0) + ldso);            \
      gl_lds16(wbase_l + (ksg) * 2048 + gsrc, CHB(buf, 1) + ldso);            \
    } while (0)

    f32x4 acc[2][2] = {};
    PSTAGE(0, sg * 4);
    __syncthreads();

    int buf = 0;
#pragma unroll 1
    for (int kl = 0; kl < 4; ++kl) {
      if (kl < 3) PSTAGE(buf ^ 1, sg * 4 + kl + 1);
      const int kgo = (l >> 4) * 1024;
      short8 ah[2], al[2], bh[2], bl[2];
#pragma unroll
      for (int i = 0; i < 2; ++i) {
        const int ro = (wr * 32 + i * 16 + (l & 15)) * 16;
        ah[i] = *reinterpret_cast<const short8*>(CHA(buf, 0) + kgo + ro);
        al[i] = *reinterpret_cast<const short8*>(CHA(buf, 1) + kgo + ro);
      }
#pragma unroll
      for (int j = 0; j < 2; ++j) {
        const int co = (wc * 32 + j * 16 + (l & 15)) * 16;
        bh[j] = *reinterpret_cast<const short8*>(CHB(buf, 0) + kgo + co);
        bl[j] = *reinterpret_cast<const short8*>(CHB(buf, 1) + kgo + co);
      }
#pragma unroll
      for (int i = 0; i < 2; ++i)
#pragma unroll
        for (int j = 0; j < 2; ++j) {
          acc[i][j] = __builtin_amdgcn_mfma_f32_16x16x32_bf16(ah[i], bh[j], acc[i][j], 0, 0, 0);
          acc[i][j] = __builtin_amdgcn_mfma_f32_16x16x32_bf16(ah[i], bl[j], acc[i][j], 0, 0, 0);
          acc[i][j] = __builtin_amdgcn_mfma_f32_16x16x32_bf16(al[i], bh[j], acc[i][j], 0, 0, 0);
        }
      __syncthreads();
      buf ^= 1;
    }

    // split-K reduction: red[4 sg][256 t][16] f32 (64 KB) aliases Ast/Bst
    float* const red = (float*)uA;
#pragma unroll
    for (int i = 0; i < 2; ++i)
#pragma unroll
      for (int j = 0; j < 2; ++j)
        *reinterpret_cast<f32x4*>(&red[((size_t)sg * 256 + t) * 16 + (i * 2 + j) * 4]) = acc[i][j];
    __syncthreads();

    // thread tid -> original-thread t2, frag fi; sum 4 partials; exp; store
    const int t2 = tid >> 2;
    const int fi = tid & 3;
    const int i2 = fi >> 1, j2 = fi & 1;
    const int base = t2 * 16 + fi * 4;
    const f4 s0 = *reinterpret_cast<const f4*>(&red[0 * 4096 + base]);
    const f4 s1 = *reinterpret_cast<const f4*>(&red[1 * 4096 + base]);
    const f4 s2 = *reinterpret_cast<const f4*>(&red[2 * 4096 + base]);
    const f4 s3 = *reinterpret_cast<const f4*>(&red[3 * 4096 + base]);
    const f4 rs = (s0 + s1) + (s2 + s3);

    const int l2  = t2 & 63;
    const int w42 = t2 >> 6;
    const int wr2 = w42 >> 1, wc2 = w42 & 1;
    const int row_local = wr2 * 32 + i2 * 16 + (l2 >> 4) * 4;
    const int col_local = wc2 * 32 + j2 * 16 + (l2 & 15);

    if (z == 0) {
#pragma unroll
      for (int r = 0; r < 4; ++r)
        EQ[(size_t)(mb * 64 + row_local + r) * 512 + nb * 64 + col_local] =
            __expf(2.0f * rs[r]);
    } else {
      float* const ldsT = (float*)(uA + 65536);   // [64][67]
      __syncthreads();   // red reads complete before aliasing? (red at 0..64K, ldsT at 64K.. -> disjoint; barrier for write/read phase order below)
#pragma unroll
      for (int r = 0; r < 4; ++r)
        ldsT[(row_local + r) * 67 + col_local] = __expf(2.0f * rs[r]);
      __syncthreads();
      const int bb = (mb * 64) >> 8;
      const int v0 = (mb * 64) & 255;
      const int vl = tid & 63;
#pragma unroll
      for (int it2 = 0; it2 < 4; ++it2) {
        const int ul = it2 * 16 + (tid >> 6);
        EKT[(size_t)bb * 131072 + (size_t)(nb * 64 + ul) * 256 + v0 + vl] =
            ldsT[vl * 67 + ul];
      }
    }
#undef PSTAGE
#undef CHA
#undef CHB
  }

  cg::this_grid().sync();

  // ===================== Phase 3: attn (R15-exact body) ====================
  {
    const int b  = (blk & 7) >> 1;                  // XCD-locality swizzle
    const int tg = (blk >> 3) + ((blk & 1) << 5);   // 0..63
    const int tq0 = tg * 4;
    const int bq  = b * 256 + tq0;

    const int v4  = tid & 63;
    const int uq  = tid >> 6;
    const int w   = tid >> 6;
    const int l   = tid & 63;

    float* const ubufF = (float*)uA;
    float* const partF = (float*)uA;
    float* const ctxpF = (float*)(uA + 65536);

    const float* __restrict__ ekb = EKT + (size_t)b * (512 * 256);
    const float* __restrict__ eqb = EQ + (size_t)bq * 512;

    const int u0 = uq * 32;
    float* const wbase = ubufF + uq * 2048;

    const int r   = w & 3;
    const int vg  = w >> 2;
    const int v   = vg * 64 + l;

#define STAGEW(bufp, s)                                                       \
    do {                                                                      \
      _Pragma("unroll")                                                       \
      for (int c_ = 0; c_ < 4; ++c_)                                          \
        gl_lds16(ekb + (size_t)(u0 + (s) * 4 + c_) * 256 + l * 4,             \
                 wbase + (bufp) * 1024 + c_ * 256);                           \
    } while (0)

    STAGEW(0, 0);

    const bool mok = (mask[b * 256 + v] != 0);

    {
      const int h  = tid >> 9;
      const int u2 = tid & 511;
      f2 e;
      e[0] = eqb[(size_t)(2 * h) * 512 + u2];
      e[1] = eqb[(size_t)(2 * h + 1) * 512 + u2];
      *(reinterpret_cast<f2*>(&eq4s[u2]) + h) = e;
      if (h == 0) ss[u2] = scale[u2];
    }
    __syncthreads();

    if (w == 0) {
      float s = 0.f;
#pragma unroll
      for (int j = 0; j < 8; ++j) s += ss[l + 64 * j];
#pragma unroll
      for (int off = 32; off; off >>= 1) s += __shfl_xor(s, off);
      if (l == 0) sumS_lds = s;
    }

    f2 accp[4][2] = {};
    int bufi = 0;
#pragma unroll 1
    for (int s = 0; s < 8; ++s) {
      if (s < 7) {
        STAGEW(bufi ^ 1, s + 1);
        asm volatile("s_waitcnt vmcnt(4)" ::: "memory");
      } else {
        asm volatile("s_waitcnt vmcnt(0)" ::: "memory");
      }
      __builtin_amdgcn_sched_barrier(0);
      const float* bp = wbase + bufi * 1024;
#pragma unroll
      for (int cp = 0; cp < 2; ++cp) {
        const int uA_ = u0 + s * 4 + 2 * cp;
        const f4 ekA4 = *reinterpret_cast<const f4*>(bp + (2 * cp) * 256 + v4 * 4);
        const f4 ekB4 = *reinterpret_cast<const f4*>(bp + (2 * cp + 1) * 256 + v4 * 4);
        const f2 ekA[2] = {{ekA4[0], ekA4[1]}, {ekA4[2], ekA4[3]}};
        const f2 ekB[2] = {{ekB4[0], ekB4[1]}, {ekB4[2], ekB4[3]}};
        const f4 eqA = eq4s[uA_];
        const f4 eqB = eq4s[uA_ + 1];
        const f2 sp  = *reinterpret_cast<const f2*>(&ss[uA_]);
        const f2 sA2 = {sp[0], sp[0]};
        const f2 sB2 = {sp[1], sp[1]};
        const f2 one2 = {1.0f, 1.0f};
#pragma unroll
        for (int i = 0; i < 4; ++i) {
          const f2 eA2 = {eqA[i], eqA[i]};
          const f2 eB2 = {eqB[i], eqB[i]};
#pragma unroll
          for (int jh = 0; jh < 2; ++jh) {
            const f2 dA  = __builtin_elementwise_fma(eA2, ekA[jh], one2);
            const f2 dB  = __builtin_elementwise_fma(eB2, ekB[jh], one2);
            const f2 num = __builtin_elementwise_fma(sA2, dB, sB2 * dA);
            const f2 P   = dA * dB;
            f2 r_;
            r_[0] = __builtin_amdgcn_rcpf(P[0]);
            r_[1] = __builtin_amdgcn_rcpf(P[1]);
            accp[i][jh] = __builtin_elementwise_fma(num, r_, accp[i][jh]);
          }
        }
      }
      bufi ^= 1;
    }

    // Phase A: in-place partials (own wave buffer; vmcnt(0) drained)
#pragma unroll
    for (int i = 0; i < 4; ++i) {
      const f4 a4 = {accp[i][0][0], accp[i][0][1], accp[i][1][0], accp[i][1][1]};
      *reinterpret_cast<f4*>(partF + uq * 2048 + i * 256 + v4 * 4) = a4;
    }
    __syncthreads();

    // Phase B
    float sc, ex;
    {
      float p = 0.f;
#pragma unroll
      for (int u2 = 0; u2 < 16; ++u2) p += partF[u2 * 2048 + r * 256 + v];
      sc = mok ? (sumS_lds - 2.0f * p) : NEG_INF;
      float m = sc;
#pragma unroll
      for (int off = 32; off; off >>= 1) m = fmaxf(m, __shfl_xor(m, off));
      if (l == 0) wredM[r][vg] = m;
    }
    __syncthreads();

    // Phase C
    {
      const float m = fmaxf(fmaxf(wredM[r][0], wredM[r][1]),
                            fmaxf(wredM[r][2], wredM[r][3]));
      ex = __expf(sc - m);
      float sm = ex;
#pragma unroll
      for (int off = 32; off; off >>= 1) sm += __shfl_xor(sm, off);
      if (l == 0) wredS[r][vg] = sm;
    }
    __syncthreads();

    // Phase D
    {
      const float denom = (wredS[r][0] + wredS[r][1]) + (wredS[r][2] + wredS[r][3]);
      const float a = ex * __builtin_amdgcn_rcpf(denom);
      atT[v][r] = a;
      attn_out[(size_t)(bq + r) * 256 + v] = a;
    }
    __syncthreads();

    // Phase E
    const int vc8 = w & 7;
    const int dh  = w >> 3;
    const float* __restrict__ vb = value + (size_t)b * (256 * 512) + dh * 256;
    f4 g0 = {0,0,0,0}, g1 = {0,0,0,0}, g2 = {0,0,0,0}, g3 = {0,0,0,0};
#pragma unroll 4
    for (int v2 = 0; v2 < 32; ++v2) {
      const int vv = vc8 * 32 + v2;
      const f4 a4 = *reinterpret_cast<const f4*>(&atT[vv][0]);
      const f4 x  = *reinterpret_cast<const f4*>(&vb[(size_t)vv * 512 + l * 4]);
      g0 += a4[0] * x;
      g1 += a4[1] * x;
      g2 += a4[2] * x;
      g3 += a4[3] * x;
    }
    {
      float* const cp = ctxpF + vc8 * 2048 + dh * 256 + l * 4;
      *reinterpret_cast<f4*>(cp + 0 * 512) = g0;
      *reinterpret_cast<f4*>(cp + 1 * 512) = g1;
      *reinterpret_cast<f4*>(cp + 2 * 512) = g2;
      *reinterpret_cast<f4*>(cp + 3 * 512) = g3;
    }
    __syncthreads();

    // Phase F
    {
      const int row = tid >> 8;
      const int d2  = (tid & 255) * 2;
      f2 s = {0.f, 0.f};
#pragma unroll
      for (int vc = 0; vc < 8; ++vc)
        s += *reinterpret_cast<const f2*>(ctxpF + vc * 2048 + row * 512 + d2);
      *reinterpret_cast<f2*>(&ctx_out[(size_t)(bq + row) * 512 + d2]) = s;
    }
#undef STAGEW
  }
}

// ---------------------------------------------------------------------------
extern "C" void kernel_launch(void* const* d_in, const int* in_sizes, int n_in,
                              void* d_out, int out_size, void* d_ws, size_t ws_size,
                              hipStream_t stream) {
  const float* query = (const float*)d_in[0];
  const float* value = (const float*)d_in[1];
  const int*   mask  = (const int*)d_in[2];
  const float* W1    = (const float*)d_in[3];
  const float* W2    = (const float*)d_in[4];
  const float* scale = (const float*)d_in[5];

  char* ws = (char*)d_ws;
  float* EQ  = (float*)(ws);                         // 2 MB
  float* EKT = (float*)(ws + (2u << 20));            // 2 MB
  unsigned short* Ahi = (unsigned short*)(ws + (4u << 20));   // 2 MB
  unsigned short* Alo = (unsigned short*)(ws + (6u << 20));   // 2 MB
  unsigned short* Whi = (unsigned short*)(ws + (8u << 20));   // 1 MB
  unsigned short* Wlo = (unsigned short*)(ws + (9u << 20));   // 1 MB

  float* ctx  = (float*)d_out;
  float* attn = ctx + 4 * 256 * 512;

  void* args[] = {
    (void*)&query, (void*)&value, (void*)&mask, (void*)&W1, (void*)&W2,
    (void*)&scale, (void*)&Ahi, (void*)&Alo, (void*)&Whi, (void*)&Wlo,
    (void*)&EQ, (void*)&EKT, (void*)&ctx, (void*)&attn
  };
  hipLaunchCooperativeKernel((const void*)bah_fused, dim3(256), dim3(1024),
                             args, 0, stream);
}